// Round 17
// baseline (1592.634 us; speedup 1.0000x reference)
//
#include <hip/hip_runtime.h>
#include <cstdint>
#include <cstddef>

typedef __attribute__((ext_vector_type(8))) short bf16x8;
typedef __attribute__((ext_vector_type(4))) float f32x4;

#define DEV __device__ __forceinline__

DEV unsigned short f2bf(float f) {
  union { float f; unsigned u; } v; v.f = f;
  unsigned r = (v.u + 0x7FFFu + ((v.u >> 16) & 1u)) >> 16;   // RNE
  return (unsigned short)r;
}

DEV unsigned short f2bf_rtz(float f) {   // truncate: 1 op, fine for P (positive)
  union { float f; unsigned u; } v; v.f = f;
  return (unsigned short)(v.u >> 16);
}

// tanh-approx GELU in exp2 domain, NaN-safe form x - x/(1+u). |err| < ~1e-3.
DEV float gelu_fast(float x) {
  float x2 = x * x;
  float arg = x * fmaf(x2, 0.10294936f, 2.3021174f);
  float u = exp2f(arg);
  return x - x / (1.0f + u);
}

DEV void gload16(const void* g, void* l) {
  // async global->LDS, 16B per lane; LDS dest = wave-uniform base + lane*16
  __builtin_amdgcn_global_load_lds(
      (__attribute__((address_space(1))) void*)const_cast<void*>(g),
      (__attribute__((address_space(3))) void*)l,
      16, 0, 0);
}

// ---------------- elementwise kernels ----------------

__global__ __launch_bounds__(256) void f2bf_kernel(const float* __restrict__ in,
                                                   unsigned short* __restrict__ out, int n4) {
  int i = blockIdx.x * 256 + threadIdx.x;
  if (i < n4) {
    float4 v = ((const float4*)in)[i];
    ushort4 o;
    o.x = f2bf(v.x); o.y = f2bf(v.y); o.z = f2bf(v.z); o.w = f2bf(v.w);
    ((ushort4*)out)[i] = o;
  }
}

__global__ __launch_bounds__(256) void rmsnorm_kernel(const float* __restrict__ x,
                                                      const float* __restrict__ w,
                                                      unsigned short* __restrict__ o) {
  const int row = blockIdx.x;
  const int tid = threadIdx.x;
  float4 v = ((const float4*)x)[(size_t)row * 256 + tid];
  float s = v.x * v.x + v.y * v.y + v.z * v.z + v.w * v.w;
#pragma unroll
  for (int m = 32; m > 0; m >>= 1) s += __shfl_xor(s, m);
  __shared__ float red[4];
  if ((tid & 63) == 0) red[tid >> 6] = s;
  __syncthreads();
  float tot = red[0] + red[1] + red[2] + red[3];
  float inv = rsqrtf(tot * (1.0f / 1024.0f) + 1e-6f);
  float4 wv = ((const float4*)w)[tid];
  ushort4 ov;
  ov.x = f2bf(v.x * inv * wv.x);
  ov.y = f2bf(v.y * inv * wv.y);
  ov.z = f2bf(v.z * inv * wv.z);
  ov.w = f2bf(v.w * inv * wv.w);
  ((ushort4*)o)[(size_t)row * 256 + tid] = ov;
}

// ---------------- 128x128 GEMM (T2 swizzle + T1 raster): out, fc2, fc1 ------
// EPI: 0 = bf16 store with Q-prescale (cols<1024, qkv), 1 = fast-gelu -> bf16,
//      2 = f32 out = Res + acc, 3 = EPI2 + OutAcc (+)= probs[row,d] * out
template <int EPI>
__global__ __launch_bounds__(256) void gemm_bf16(const unsigned short* __restrict__ A,
                                                 const unsigned short* __restrict__ W,
                                                 unsigned short* __restrict__ Ob,
                                                 float* __restrict__ Of,
                                                 const float* __restrict__ Res,
                                                 float* __restrict__ OutAcc,
                                                 const float* __restrict__ probs,
                                                 int dIdx, int init,
                                                 int M, int N, int K) {
  __shared__ alignas(16) unsigned short As[128 * 64];
  __shared__ alignas(16) unsigned short Bs[128 * 64];
  const int tid = threadIdx.x;
  const int lane = tid & 63;
  const int wave = tid >> 6;
  const int wr = wave >> 1, wc = wave & 1;

  // XCD chunk + 8-row super-tile raster (nwg%8==0, gridDim.y%8==0)
  int bid = blockIdx.y * gridDim.x + blockIdx.x;
  const int nwg = gridDim.x * gridDim.y;
  bid = (bid & 7) * (nwg >> 3) + (bid >> 3);
  const int span = gridDim.x << 3;
  const int sg = bid / span;
  const int rem = bid % span;
  const int bx = rem >> 3;
  const int by = (sg << 3) + (rem & 7);

  const int brow = by * 128;
  const int bcol = bx * 128;

  f32x4 acc[4][4] = {};

  const int sr = tid >> 3;
  const int sc = ((tid & 7) ^ ((tid >> 3) & 7)) << 3;    // inverse-swizzled source col
  const int ro = lane & 15;
  const int rg = lane >> 4;
  const int rsw = (ro & 7) << 3;                         // read-side swizzle

  const unsigned short* aPtr = A + (size_t)(brow + sr) * K + sc;
  const unsigned short* wPtr = W + (size_t)(bcol + sr) * K + sc;
  const size_t rowStride32 = (size_t)32 * K;

  for (int kt = 0; kt < K; kt += 64) {
#pragma unroll
    for (int i = 0; i < 4; i++) {
      gload16(aPtr + i * rowStride32, &As[i * 2048 + wave * 512]);
      gload16(wPtr + i * rowStride32, &Bs[i * 2048 + wave * 512]);
    }
    aPtr += 64;
    wPtr += 64;
    __syncthreads();
#pragma unroll
    for (int kk = 0; kk < 2; kk++) {
      const int ko = kk * 32 + rg * 8;
      bf16x8 av[4], bv[4];
#pragma unroll
      for (int m2 = 0; m2 < 4; m2++)
        av[m2] = *(const bf16x8*)&As[(wr * 64 + m2 * 16 + ro) * 64 + (ko ^ rsw)];
#pragma unroll
      for (int n2 = 0; n2 < 4; n2++)
        bv[n2] = *(const bf16x8*)&Bs[(wc * 64 + n2 * 16 + ro) * 64 + (ko ^ rsw)];
#pragma unroll
      for (int m2 = 0; m2 < 4; m2++)
#pragma unroll
        for (int n2 = 0; n2 < 4; n2++)
          acc[m2][n2] = __builtin_amdgcn_mfma_f32_16x16x32_bf16(av[m2], bv[n2], acc[m2][n2], 0, 0, 0);
    }
    __syncthreads();
  }

#pragma unroll
  for (int m2 = 0; m2 < 4; m2++) {
#pragma unroll
    for (int i = 0; i < 4; i++) {
      const int row = brow + wr * 64 + m2 * 16 + rg * 4 + i;
#pragma unroll
      for (int n2 = 0; n2 < 4; n2++) {
        const int col = bcol + wc * 64 + n2 * 16 + ro;
        const size_t idx = (size_t)row * N + col;
        float v = acc[m2][n2][i];
        if (EPI == 0) {
          float s2 = (col < 1024) ? 0.18033688f : 1.0f;
          Ob[idx] = f2bf(v * s2);
        } else if (EPI == 1) {
          Ob[idx] = f2bf(gelu_fast(v));
        } else if (EPI == 2) {
          Of[idx] = Res[idx] + v;
        } else {
          float nv = Res[idx] + v;
          Of[idx] = nv;
          float p = probs[(size_t)row * 4 + dIdx];
          float o = init ? 0.f : OutAcc[idx];
          OutAcc[idx] = o + p * nv;
        }
      }
    }
  }
}

// ---------------- 256x128 GEMM, per-wave 128x64 (acc 8x4) for qkv ------------
// EPI: 0 = bf16 store with Q-prescale (cols<1024, for qkv), 1 = fast-gelu bf16.
template <int EPI>
__global__ __launch_bounds__(256, 2) void gemm_m256(const unsigned short* __restrict__ A,
                                                    const unsigned short* __restrict__ W,
                                                    unsigned short* __restrict__ Ob,
                                                    int M, int N, int K) {
  __shared__ alignas(16) unsigned short As[256 * 64];
  __shared__ alignas(16) unsigned short Bs[128 * 64];
  const int tid = threadIdx.x;
  const int lane = tid & 63;
  const int wave = tid >> 6;
  const int wr = wave >> 1, wc = wave & 1;

  // XCD chunk + 8-row super-tile raster (nwg%8==0, gridDim.y == M/256 == 32)
  int bid = blockIdx.y * gridDim.x + blockIdx.x;
  const int nwg = gridDim.x * gridDim.y;
  bid = (bid & 7) * (nwg >> 3) + (bid >> 3);
  const int span = gridDim.x << 3;
  const int sg = bid / span;
  const int rem = bid % span;
  const int bx = rem >> 3;
  const int by = (sg << 3) + (rem & 7);

  const int brow = by * 256;
  const int bcol = bx * 128;

  f32x4 acc[8][4] = {};

  const int sr = tid >> 3;
  const int sc = ((tid & 7) ^ ((tid >> 3) & 7)) << 3;    // inverse-swizzled source col
  const int ro = lane & 15;
  const int rg = lane >> 4;
  const int rsw = (ro & 7) << 3;                         // read-side swizzle

  const unsigned short* aPtr = A + (size_t)(brow + sr) * K + sc;
  const unsigned short* wPtr = W + (size_t)(bcol + sr) * K + sc;
  const size_t rowStride32 = (size_t)32 * K;

  for (int kt = 0; kt < K; kt += 64) {
#pragma unroll
    for (int i = 0; i < 8; i++)
      gload16(aPtr + i * rowStride32, &As[i * 2048 + wave * 512]);
#pragma unroll
    for (int i = 0; i < 4; i++)
      gload16(wPtr + i * rowStride32, &Bs[i * 2048 + wave * 512]);
    aPtr += 64;
    wPtr += 64;
    __syncthreads();
#pragma unroll
    for (int kk = 0; kk < 2; kk++) {
      const int ko = kk * 32 + rg * 8;
      bf16x8 av[8], bv[4];
#pragma unroll
      for (int m2 = 0; m2 < 8; m2++)
        av[m2] = *(const bf16x8*)&As[(wr * 128 + m2 * 16 + ro) * 64 + (ko ^ rsw)];
#pragma unroll
      for (int n2 = 0; n2 < 4; n2++)
        bv[n2] = *(const bf16x8*)&Bs[(wc * 64 + n2 * 16 + ro) * 64 + (ko ^ rsw)];
#pragma unroll
      for (int m2 = 0; m2 < 8; m2++)
#pragma unroll
        for (int n2 = 0; n2 < 4; n2++)
          acc[m2][n2] = __builtin_amdgcn_mfma_f32_16x16x32_bf16(av[m2], bv[n2], acc[m2][n2], 0, 0, 0);
    }
    __syncthreads();
  }

#pragma unroll
  for (int m2 = 0; m2 < 8; m2++) {
#pragma unroll
    for (int i = 0; i < 4; i++) {
      const int row = brow + wr * 128 + m2 * 16 + rg * 4 + i;
#pragma unroll
      for (int n2 = 0; n2 < 4; n2++) {
        const int col = bcol + wc * 64 + n2 * 16 + ro;
        const size_t idx = (size_t)row * N + col;
        float v = acc[m2][n2][i];
        if (EPI == 0) {
          float s2 = (col < 1024) ? 0.18033688f : 1.0f;   // pre-scale Q into log2 domain
          Ob[idx] = f2bf(v * s2);
        } else {
          Ob[idx] = f2bf(gelu_fast(v));
        }
      }
    }
  }
}

// ---------------- flash attention (r14, unchanged) ----------------
// 8 waves/block (512 thr), 128 q-rows/block, 16 q-rows/wave. One K/V stage
// serves 8 waves. (512,4): VGPR cap ~128, no spill; LDS 36.9KB -> 4 blk/CU.
__global__ __launch_bounds__(512, 4) void attn_kernel(const unsigned short* __restrict__ qkv,
                                                      unsigned short* __restrict__ ob) {
  __shared__ alignas(16) unsigned short kt[64][72];
  __shared__ alignas(16) unsigned short vt[64][72];
  __shared__ alignas(16) unsigned short pt[8][16][72];
  const int tid = threadIdx.x, lane = tid & 63, wave = tid >> 6;

  const int nwg = gridDim.x * gridDim.y;   // 1024, %8==0
  int bid = blockIdx.y * gridDim.x + blockIdx.x;
  bid = (bid & 7) * (nwg >> 3) + (bid >> 3);
  const int qt = bid % gridDim.x;
  const int bh = bid / gridDim.x;
  const int b = bh >> 4, h = bh & 15;

  const size_t base = (size_t)b * 1024 * 3072 + (size_t)h * 64;
  const unsigned short* qp = qkv + base;
  const int q0 = qt * 128 + wave * 16;
  const int ro = lane & 15, rg = lane >> 4;

  bf16x8 aq[2];
  aq[0] = *(const bf16x8*)&qp[(size_t)(q0 + ro) * 3072 + rg * 8];
  aq[1] = *(const bf16x8*)&qp[(size_t)(q0 + ro) * 3072 + 32 + rg * 8];

  // staging: 512 threads cover 64 rows x 64 cols in ONE pass (1 uint4 K + 1 uint4 V each)
  const int sr0 = tid >> 3, sci = tid & 7, scl = sci << 3;
  const unsigned short* kRow = qkv + base + 1024 + (size_t)sr0 * 3072 + scl;
  const unsigned short* vRow = qkv + base + 2048 + (size_t)sr0 * 3072 + scl;

  f32x4 oacc[4] = {};
  float mrow[4] = {-1e30f, -1e30f, -1e30f, -1e30f};  // group-uniform by construction
  float lrow[4] = {0.f, 0.f, 0.f, 0.f};              // per-lane partials, reduced at end

  for (int t0 = 0; t0 < 1024; t0 += 64) {
    {
      uint4 k0 = *(const uint4*)kRow;
      uint4 v0 = *(const uint4*)vRow;
      *(uint4*)&kt[sr0][scl] = k0;
      const unsigned short* e0 = (const unsigned short*)&v0;
#pragma unroll
      for (int j = 0; j < 8; j++) {
        const int jj = (j + sci) & 7;   // rotation: 8 same-row lanes -> 8 banks
        vt[scl + jj][sr0] = e0[jj];
      }
      kRow += 64 * 3072;
      vRow += 64 * 3072;
    }
    __syncthreads();

    // S = Q K^T  (Q pre-scaled by 1/8*log2e in the qkv GEMM epilogue)
    f32x4 sf[4] = {};
#pragma unroll
    for (int kk = 0; kk < 2; kk++) {
      const int ko = kk * 32 + rg * 8;
#pragma unroll
      for (int n2 = 0; n2 < 4; n2++) {
        bf16x8 bk = *(const bf16x8*)&kt[n2 * 16 + ro][ko];
        sf[n2] = __builtin_amdgcn_mfma_f32_16x16x32_bf16(aq[kk], bk, sf[n2], 0, 0, 0);
      }
    }

    // lane-local max only (no shuffles on common path)
    float lmax[4];
#pragma unroll
    for (int i = 0; i < 4; i++)
      lmax[i] = fmaxf(fmaxf(sf[0][i], sf[1][i]), fmaxf(sf[2][i], sf[3][i]));
    bool need = (lmax[0] > mrow[0] + 8.f) | (lmax[1] > mrow[1] + 8.f) |
                (lmax[2] > mrow[2] + 8.f) | (lmax[3] > mrow[3] + 8.f);
    if (__any(need)) {
#pragma unroll
      for (int msk = 1; msk < 16; msk <<= 1)
#pragma unroll
        for (int i = 0; i < 4; i++) lmax[i] = fmaxf(lmax[i], __shfl_xor(lmax[i], msk));
#pragma unroll
      for (int i = 0; i < 4; i++) {
        float mn = fmaxf(mrow[i], lmax[i]);
        float alpha = exp2f(mrow[i] - mn);   // group-uniform
        mrow[i] = mn;
        lrow[i] *= alpha;
#pragma unroll
        for (int n2 = 0; n2 < 4; n2++) oacc[n2][i] *= alpha;
      }
    }
#pragma unroll
    for (int n2 = 0; n2 < 4; n2++)
#pragma unroll
      for (int i = 0; i < 4; i++) {
        sf[n2][i] = exp2f(sf[n2][i] - mrow[i]);
        lrow[i] += sf[n2][i];
      }

#pragma unroll
    for (int n2 = 0; n2 < 4; n2++)
#pragma unroll
      for (int i = 0; i < 4; i++)
        pt[wave][rg * 4 + i][n2 * 16 + ro] = f2bf_rtz(sf[n2][i]);
    asm volatile("" ::: "memory");  // same-wave DS in-order; keep writes before reads

    // O += P @ V
#pragma unroll
    for (int kk = 0; kk < 2; kk++) {
      const int ko = kk * 32 + rg * 8;
      bf16x8 ap = *(const bf16x8*)&pt[wave][ro][ko];
#pragma unroll
      for (int n2 = 0; n2 < 4; n2++) {
        bf16x8 bv2 = *(const bf16x8*)&vt[n2 * 16 + ro][ko];
        oacc[n2] = __builtin_amdgcn_mfma_f32_16x16x32_bf16(ap, bv2, oacc[n2], 0, 0, 0);
      }
    }
    __syncthreads();
  }

  // final row-sum reduce across the 16-lane group
#pragma unroll
  for (int msk = 1; msk < 16; msk <<= 1)
#pragma unroll
    for (int i = 0; i < 4; i++) lrow[i] += __shfl_xor(lrow[i], msk);

#pragma unroll
  for (int n2 = 0; n2 < 4; n2++)
#pragma unroll
    for (int i = 0; i < 4; i++) {
      const int qrow = q0 + rg * 4 + i;
      float v = oacc[n2][i] / lrow[i];
      ob[((size_t)b * 1024 + qrow) * 1024 + h * 64 + n2 * 16 + ro] = f2bf(v);
    }
}

// ---------------- host ----------------

extern "C" void kernel_launch(void* const* d_in, const int* in_sizes, int n_in,
                              void* d_out, int out_size, void* d_ws, size_t ws_size,
                              hipStream_t stream) {
  const float* x = (const float*)d_in[0];
  const float* probs = (const float*)d_in[2];
  const float* n1w = (const float*)d_in[3];
  const float* qkvw = (const float*)d_in[4];
  const float* outw = (const float*)d_in[5];
  const float* n2w = (const float*)d_in[6];
  const float* fc1w = (const float*)d_in[7];
  const float* fc2w = (const float*)d_in[8];
  float* out = (float*)d_out;

  const int B = 8, T = 1024, C = 1024;
  const int M = B * T;  // 8192

  char* ws = (char*)d_ws;
  size_t off = 0;
  auto alloc = [&](size_t bytes) {
    void* p = ws + off;
    off += (bytes + 255) & ~(size_t)255;
    return p;
  };
  unsigned short* wqkv = (unsigned short*)alloc((size_t)3072 * 1024 * 2);
  unsigned short* wout = (unsigned short*)alloc((size_t)1024 * 1024 * 2);
  unsigned short* wfc1 = (unsigned short*)alloc((size_t)4096 * 1024 * 2);
  unsigned short* wfc2 = (unsigned short*)alloc((size_t)1024 * 4096 * 2);
  float* xb = (float*)alloc((size_t)M * C * 4);
  unsigned short* xn = (unsigned short*)alloc((size_t)M * C * 2);
  char* big = (char*)alloc((size_t)M * 4096 * 2);
  unsigned short* qkvb = (unsigned short*)big;
  unsigned short* obuf = (unsigned short*)(big + (size_t)M * 3072 * 2);
  unsigned short* gbuf = (unsigned short*)big;

  f2bf_kernel<<<(3072 * 1024 / 4 + 255) / 256, 256, 0, stream>>>(qkvw, wqkv, 3072 * 1024 / 4);
  f2bf_kernel<<<(1024 * 1024 / 4 + 255) / 256, 256, 0, stream>>>(outw, wout, 1024 * 1024 / 4);
  f2bf_kernel<<<(4096 * 1024 / 4 + 255) / 256, 256, 0, stream>>>(fc1w, wfc1, 4096 * 1024 / 4);
  f2bf_kernel<<<(4096 * 1024 / 4 + 255) / 256, 256, 0, stream>>>(fc2w, wfc2, 4096 * 1024 / 4);

  hipMemcpyAsync(xb, x, (size_t)M * C * 4, hipMemcpyDeviceToDevice, stream);

  for (int d = 0; d < 4; d++) {
    rmsnorm_kernel<<<M, 256, 0, stream>>>(xb, n1w, xn);
    gemm_m256<0><<<dim3(3072 / 128, M / 256), 256, 0, stream>>>(xn, wqkv, qkvb, M, 3072, 1024);
    attn_kernel<<<dim3(T / 128, B * 16), 512, 0, stream>>>(qkvb, obuf);
    gemm_bf16<2><<<dim3(1024 / 128, M / 128), 256, 0, stream>>>(
        obuf, wout, nullptr, xb, xb, nullptr, nullptr, 0, 0, M, 1024, 1024);
    rmsnorm_kernel<<<M, 256, 0, stream>>>(xb, n2w, xn);
    gemm_bf16<1><<<dim3(4096 / 128, M / 128), 256, 0, stream>>>(
        xn, wfc1, gbuf, nullptr, nullptr, nullptr, nullptr, 0, 0, M, 4096, 1024);
    gemm_bf16<3><<<dim3(1024 / 128, M / 128), 256, 0, stream>>>(
        gbuf, wfc2, nullptr, xb, xb, out, probs, d, d == 0 ? 1 : 0, M, 1024, 4096);
  }
}

// Round 18
// 1516.132 us; speedup vs baseline: 1.0505x; 1.0505x over previous
//
#include <hip/hip_runtime.h>
#include <cstdint>
#include <cstddef>

typedef __attribute__((ext_vector_type(8))) short bf16x8;
typedef __attribute__((ext_vector_type(4))) float f32x4;

#define DEV __device__ __forceinline__

DEV unsigned short f2bf(float f) {
  union { float f; unsigned u; } v; v.f = f;
  unsigned r = (v.u + 0x7FFFu + ((v.u >> 16) & 1u)) >> 16;   // RNE
  return (unsigned short)r;
}

DEV unsigned short f2bf_rtz(float f) {   // truncate: 1 op, fine for P (positive)
  union { float f; unsigned u; } v; v.f = f;
  return (unsigned short)(v.u >> 16);
}

// tanh-approx GELU in exp2 domain, NaN-safe form x - x/(1+u). |err| < ~1e-3.
DEV float gelu_fast(float x) {
  float x2 = x * x;
  float arg = x * fmaf(x2, 0.10294936f, 2.3021174f);
  float u = exp2f(arg);
  return x - x / (1.0f + u);
}

DEV void gload16(const void* g, void* l) {
  // async global->LDS, 16B per lane; LDS dest = wave-uniform base + lane*16
  __builtin_amdgcn_global_load_lds(
      (__attribute__((address_space(1))) void*)const_cast<void*>(g),
      (__attribute__((address_space(3))) void*)l,
      16, 0, 0);
}

// ---------------- elementwise kernels ----------------

__global__ __launch_bounds__(256) void f2bf_kernel(const float* __restrict__ in,
                                                   unsigned short* __restrict__ out, int n4) {
  int i = blockIdx.x * 256 + threadIdx.x;
  if (i < n4) {
    float4 v = ((const float4*)in)[i];
    ushort4 o;
    o.x = f2bf(v.x); o.y = f2bf(v.y); o.z = f2bf(v.z); o.w = f2bf(v.w);
    ((ushort4*)out)[i] = o;
  }
}

__global__ __launch_bounds__(256) void rmsnorm_kernel(const float* __restrict__ x,
                                                      const float* __restrict__ w,
                                                      unsigned short* __restrict__ o) {
  const int row = blockIdx.x;
  const int tid = threadIdx.x;
  float4 v = ((const float4*)x)[(size_t)row * 256 + tid];
  float s = v.x * v.x + v.y * v.y + v.z * v.z + v.w * v.w;
#pragma unroll
  for (int m = 32; m > 0; m >>= 1) s += __shfl_xor(s, m);
  __shared__ float red[4];
  if ((tid & 63) == 0) red[tid >> 6] = s;
  __syncthreads();
  float tot = red[0] + red[1] + red[2] + red[3];
  float inv = rsqrtf(tot * (1.0f / 1024.0f) + 1e-6f);
  float4 wv = ((const float4*)w)[tid];
  ushort4 ov;
  ov.x = f2bf(v.x * inv * wv.x);
  ov.y = f2bf(v.y * inv * wv.y);
  ov.z = f2bf(v.z * inv * wv.z);
  ov.w = f2bf(v.w * inv * wv.w);
  ((ushort4*)o)[(size_t)row * 256 + tid] = ov;
}

// ---------------- 128x128 GEMM (T2 swizzle + T1 raster) for N=1024: out, fc2 -
// EPI: 2 = f32 out = Res + acc, 3 = EPI2 + OutAcc (+)= probs[row,d] * out
template <int EPI>
__global__ __launch_bounds__(256) void gemm_bf16(const unsigned short* __restrict__ A,
                                                 const unsigned short* __restrict__ W,
                                                 float* __restrict__ Of,
                                                 const float* __restrict__ Res,
                                                 float* __restrict__ OutAcc,
                                                 const float* __restrict__ probs,
                                                 int dIdx, int init,
                                                 int M, int N, int K) {
  __shared__ alignas(16) unsigned short As[128 * 64];
  __shared__ alignas(16) unsigned short Bs[128 * 64];
  const int tid = threadIdx.x;
  const int lane = tid & 63;
  const int wave = tid >> 6;
  const int wr = wave >> 1, wc = wave & 1;

  // XCD chunk + 8-row super-tile raster (nwg%8==0, gridDim.y%8==0)
  int bid = blockIdx.y * gridDim.x + blockIdx.x;
  const int nwg = gridDim.x * gridDim.y;
  bid = (bid & 7) * (nwg >> 3) + (bid >> 3);
  const int span = gridDim.x << 3;
  const int sg = bid / span;
  const int rem = bid % span;
  const int bx = rem >> 3;
  const int by = (sg << 3) + (rem & 7);

  const int brow = by * 128;
  const int bcol = bx * 128;

  f32x4 acc[4][4] = {};

  const int sr = tid >> 3;
  const int sc = ((tid & 7) ^ ((tid >> 3) & 7)) << 3;    // inverse-swizzled source col
  const int ro = lane & 15;
  const int rg = lane >> 4;
  const int rsw = (ro & 7) << 3;                         // read-side swizzle

  const unsigned short* aPtr = A + (size_t)(brow + sr) * K + sc;
  const unsigned short* wPtr = W + (size_t)(bcol + sr) * K + sc;
  const size_t rowStride32 = (size_t)32 * K;

  for (int kt = 0; kt < K; kt += 64) {
#pragma unroll
    for (int i = 0; i < 4; i++) {
      gload16(aPtr + i * rowStride32, &As[i * 2048 + wave * 512]);
      gload16(wPtr + i * rowStride32, &Bs[i * 2048 + wave * 512]);
    }
    aPtr += 64;
    wPtr += 64;
    __syncthreads();
#pragma unroll
    for (int kk = 0; kk < 2; kk++) {
      const int ko = kk * 32 + rg * 8;
      bf16x8 av[4], bv[4];
#pragma unroll
      for (int m2 = 0; m2 < 4; m2++)
        av[m2] = *(const bf16x8*)&As[(wr * 64 + m2 * 16 + ro) * 64 + (ko ^ rsw)];
#pragma unroll
      for (int n2 = 0; n2 < 4; n2++)
        bv[n2] = *(const bf16x8*)&Bs[(wc * 64 + n2 * 16 + ro) * 64 + (ko ^ rsw)];
#pragma unroll
      for (int m2 = 0; m2 < 4; m2++)
#pragma unroll
        for (int n2 = 0; n2 < 4; n2++)
          acc[m2][n2] = __builtin_amdgcn_mfma_f32_16x16x32_bf16(av[m2], bv[n2], acc[m2][n2], 0, 0, 0);
    }
    __syncthreads();
  }

#pragma unroll
  for (int m2 = 0; m2 < 4; m2++) {
#pragma unroll
    for (int i = 0; i < 4; i++) {
      const int row = brow + wr * 64 + m2 * 16 + rg * 4 + i;
#pragma unroll
      for (int n2 = 0; n2 < 4; n2++) {
        const int col = bcol + wc * 64 + n2 * 16 + ro;
        const size_t idx = (size_t)row * N + col;
        float v = acc[m2][n2][i];
        if (EPI == 2) {
          Of[idx] = Res[idx] + v;
        } else {
          float nv = Res[idx] + v;
          Of[idx] = nv;
          float p = probs[(size_t)row * 4 + dIdx];
          float o = init ? 0.f : OutAcc[idx];
          OutAcc[idx] = o + p * nv;
        }
      }
    }
  }
}

// ---------------- 256x128 GEMM, per-wave 128x64 (acc 8x4) for qkv & fc1 ------
// EPI: 0 = bf16 store with Q-prescale (cols<1024, for qkv), 1 = fast-gelu bf16.
template <int EPI>
__global__ __launch_bounds__(256, 2) void gemm_m256(const unsigned short* __restrict__ A,
                                                    const unsigned short* __restrict__ W,
                                                    unsigned short* __restrict__ Ob,
                                                    int M, int N, int K) {
  __shared__ alignas(16) unsigned short As[256 * 64];
  __shared__ alignas(16) unsigned short Bs[128 * 64];
  const int tid = threadIdx.x;
  const int lane = tid & 63;
  const int wave = tid >> 6;
  const int wr = wave >> 1, wc = wave & 1;

  // XCD chunk + 8-row super-tile raster (nwg%8==0, gridDim.y == M/256 == 32)
  int bid = blockIdx.y * gridDim.x + blockIdx.x;
  const int nwg = gridDim.x * gridDim.y;
  bid = (bid & 7) * (nwg >> 3) + (bid >> 3);
  const int span = gridDim.x << 3;
  const int sg = bid / span;
  const int rem = bid % span;
  const int bx = rem >> 3;
  const int by = (sg << 3) + (rem & 7);

  const int brow = by * 256;
  const int bcol = bx * 128;

  f32x4 acc[8][4] = {};

  const int sr = tid >> 3;
  const int sc = ((tid & 7) ^ ((tid >> 3) & 7)) << 3;    // inverse-swizzled source col
  const int ro = lane & 15;
  const int rg = lane >> 4;
  const int rsw = (ro & 7) << 3;                         // read-side swizzle

  const unsigned short* aPtr = A + (size_t)(brow + sr) * K + sc;
  const unsigned short* wPtr = W + (size_t)(bcol + sr) * K + sc;
  const size_t rowStride32 = (size_t)32 * K;

  for (int kt = 0; kt < K; kt += 64) {
#pragma unroll
    for (int i = 0; i < 8; i++)
      gload16(aPtr + i * rowStride32, &As[i * 2048 + wave * 512]);
#pragma unroll
    for (int i = 0; i < 4; i++)
      gload16(wPtr + i * rowStride32, &Bs[i * 2048 + wave * 512]);
    aPtr += 64;
    wPtr += 64;
    __syncthreads();
#pragma unroll
    for (int kk = 0; kk < 2; kk++) {
      const int ko = kk * 32 + rg * 8;
      bf16x8 av[8], bv[4];
#pragma unroll
      for (int m2 = 0; m2 < 8; m2++)
        av[m2] = *(const bf16x8*)&As[(wr * 128 + m2 * 16 + ro) * 64 + (ko ^ rsw)];
#pragma unroll
      for (int n2 = 0; n2 < 4; n2++)
        bv[n2] = *(const bf16x8*)&Bs[(wc * 64 + n2 * 16 + ro) * 64 + (ko ^ rsw)];
#pragma unroll
      for (int m2 = 0; m2 < 8; m2++)
#pragma unroll
        for (int n2 = 0; n2 < 4; n2++)
          acc[m2][n2] = __builtin_amdgcn_mfma_f32_16x16x32_bf16(av[m2], bv[n2], acc[m2][n2], 0, 0, 0);
    }
    __syncthreads();
  }

#pragma unroll
  for (int m2 = 0; m2 < 8; m2++) {
#pragma unroll
    for (int i = 0; i < 4; i++) {
      const int row = brow + wr * 128 + m2 * 16 + rg * 4 + i;
#pragma unroll
      for (int n2 = 0; n2 < 4; n2++) {
        const int col = bcol + wc * 64 + n2 * 16 + ro;
        const size_t idx = (size_t)row * N + col;
        float v = acc[m2][n2][i];
        if (EPI == 0) {
          float s2 = (col < 1024) ? 0.18033688f : 1.0f;   // pre-scale Q into log2 domain
          Ob[idx] = f2bf(v * s2);
        } else {
          Ob[idx] = f2bf(gelu_fast(v));
        }
      }
    }
  }
}

// ---------------- flash attention (r14, unchanged) ----------------
// 8 waves/block (512 thr), 128 q-rows/block, 16 q-rows/wave. One K/V stage
// serves 8 waves. (512,4): VGPR cap ~128, no spill; LDS 36.9KB -> 4 blk/CU.
__global__ __launch_bounds__(512, 4) void attn_kernel(const unsigned short* __restrict__ qkv,
                                                      unsigned short* __restrict__ ob) {
  __shared__ alignas(16) unsigned short kt[64][72];
  __shared__ alignas(16) unsigned short vt[64][72];
  __shared__ alignas(16) unsigned short pt[8][16][72];
  const int tid = threadIdx.x, lane = tid & 63, wave = tid >> 6;

  const int nwg = gridDim.x * gridDim.y;   // 1024, %8==0
  int bid = blockIdx.y * gridDim.x + blockIdx.x;
  bid = (bid & 7) * (nwg >> 3) + (bid >> 3);
  const int qt = bid % gridDim.x;
  const int bh = bid / gridDim.x;
  const int b = bh >> 4, h = bh & 15;

  const size_t base = (size_t)b * 1024 * 3072 + (size_t)h * 64;
  const unsigned short* qp = qkv + base;
  const int q0 = qt * 128 + wave * 16;
  const int ro = lane & 15, rg = lane >> 4;

  bf16x8 aq[2];
  aq[0] = *(const bf16x8*)&qp[(size_t)(q0 + ro) * 3072 + rg * 8];
  aq[1] = *(const bf16x8*)&qp[(size_t)(q0 + ro) * 3072 + 32 + rg * 8];

  // staging: 512 threads cover 64 rows x 64 cols in ONE pass (1 uint4 K + 1 uint4 V each)
  const int sr0 = tid >> 3, sci = tid & 7, scl = sci << 3;
  const unsigned short* kRow = qkv + base + 1024 + (size_t)sr0 * 3072 + scl;
  const unsigned short* vRow = qkv + base + 2048 + (size_t)sr0 * 3072 + scl;

  f32x4 oacc[4] = {};
  float mrow[4] = {-1e30f, -1e30f, -1e30f, -1e30f};  // group-uniform by construction
  float lrow[4] = {0.f, 0.f, 0.f, 0.f};              // per-lane partials, reduced at end

  for (int t0 = 0; t0 < 1024; t0 += 64) {
    {
      uint4 k0 = *(const uint4*)kRow;
      uint4 v0 = *(const uint4*)vRow;
      *(uint4*)&kt[sr0][scl] = k0;
      const unsigned short* e0 = (const unsigned short*)&v0;
#pragma unroll
      for (int j = 0; j < 8; j++) {
        const int jj = (j + sci) & 7;   // rotation: 8 same-row lanes -> 8 banks
        vt[scl + jj][sr0] = e0[jj];
      }
      kRow += 64 * 3072;
      vRow += 64 * 3072;
    }
    __syncthreads();

    // S = Q K^T  (Q pre-scaled by 1/8*log2e in the qkv GEMM epilogue)
    f32x4 sf[4] = {};
#pragma unroll
    for (int kk = 0; kk < 2; kk++) {
      const int ko = kk * 32 + rg * 8;
#pragma unroll
      for (int n2 = 0; n2 < 4; n2++) {
        bf16x8 bk = *(const bf16x8*)&kt[n2 * 16 + ro][ko];
        sf[n2] = __builtin_amdgcn_mfma_f32_16x16x32_bf16(aq[kk], bk, sf[n2], 0, 0, 0);
      }
    }

    // lane-local max only (no shuffles on common path)
    float lmax[4];
#pragma unroll
    for (int i = 0; i < 4; i++)
      lmax[i] = fmaxf(fmaxf(sf[0][i], sf[1][i]), fmaxf(sf[2][i], sf[3][i]));
    bool need = (lmax[0] > mrow[0] + 8.f) | (lmax[1] > mrow[1] + 8.f) |
                (lmax[2] > mrow[2] + 8.f) | (lmax[3] > mrow[3] + 8.f);
    if (__any(need)) {
#pragma unroll
      for (int msk = 1; msk < 16; msk <<= 1)
#pragma unroll
        for (int i = 0; i < 4; i++) lmax[i] = fmaxf(lmax[i], __shfl_xor(lmax[i], msk));
#pragma unroll
      for (int i = 0; i < 4; i++) {
        float mn = fmaxf(mrow[i], lmax[i]);
        float alpha = exp2f(mrow[i] - mn);   // group-uniform
        mrow[i] = mn;
        lrow[i] *= alpha;
#pragma unroll
        for (int n2 = 0; n2 < 4; n2++) oacc[n2][i] *= alpha;
      }
    }
#pragma unroll
    for (int n2 = 0; n2 < 4; n2++)
#pragma unroll
      for (int i = 0; i < 4; i++) {
        sf[n2][i] = exp2f(sf[n2][i] - mrow[i]);
        lrow[i] += sf[n2][i];
      }

#pragma unroll
    for (int n2 = 0; n2 < 4; n2++)
#pragma unroll
      for (int i = 0; i < 4; i++)
        pt[wave][rg * 4 + i][n2 * 16 + ro] = f2bf_rtz(sf[n2][i]);
    asm volatile("" ::: "memory");  // same-wave DS in-order; keep writes before reads

    // O += P @ V
#pragma unroll
    for (int kk = 0; kk < 2; kk++) {
      const int ko = kk * 32 + rg * 8;
      bf16x8 ap = *(const bf16x8*)&pt[wave][ro][ko];
#pragma unroll
      for (int n2 = 0; n2 < 4; n2++) {
        bf16x8 bv2 = *(const bf16x8*)&vt[n2 * 16 + ro][ko];
        oacc[n2] = __builtin_amdgcn_mfma_f32_16x16x32_bf16(ap, bv2, oacc[n2], 0, 0, 0);
      }
    }
    __syncthreads();
  }

  // final row-sum reduce across the 16-lane group
#pragma unroll
  for (int msk = 1; msk < 16; msk <<= 1)
#pragma unroll
    for (int i = 0; i < 4; i++) lrow[i] += __shfl_xor(lrow[i], msk);

#pragma unroll
  for (int n2 = 0; n2 < 4; n2++)
#pragma unroll
    for (int i = 0; i < 4; i++) {
      const int qrow = q0 + rg * 4 + i;
      float v = oacc[n2][i] / lrow[i];
      ob[((size_t)b * 1024 + qrow) * 1024 + h * 64 + n2 * 16 + ro] = f2bf(v);
    }
}

// ---------------- host ----------------

extern "C" void kernel_launch(void* const* d_in, const int* in_sizes, int n_in,
                              void* d_out, int out_size, void* d_ws, size_t ws_size,
                              hipStream_t stream) {
  const float* x = (const float*)d_in[0];
  const float* probs = (const float*)d_in[2];
  const float* n1w = (const float*)d_in[3];
  const float* qkvw = (const float*)d_in[4];
  const float* outw = (const float*)d_in[5];
  const float* n2w = (const float*)d_in[6];
  const float* fc1w = (const float*)d_in[7];
  const float* fc2w = (const float*)d_in[8];
  float* out = (float*)d_out;

  const int B = 8, T = 1024, C = 1024;
  const int M = B * T;  // 8192

  char* ws = (char*)d_ws;
  size_t off = 0;
  auto alloc = [&](size_t bytes) {
    void* p = ws + off;
    off += (bytes + 255) & ~(size_t)255;
    return p;
  };
  unsigned short* wqkv = (unsigned short*)alloc((size_t)3072 * 1024 * 2);
  unsigned short* wout = (unsigned short*)alloc((size_t)1024 * 1024 * 2);
  unsigned short* wfc1 = (unsigned short*)alloc((size_t)4096 * 1024 * 2);
  unsigned short* wfc2 = (unsigned short*)alloc((size_t)1024 * 4096 * 2);
  float* xb = (float*)alloc((size_t)M * C * 4);
  unsigned short* xn = (unsigned short*)alloc((size_t)M * C * 2);
  char* big = (char*)alloc((size_t)M * 4096 * 2);
  unsigned short* qkvb = (unsigned short*)big;
  unsigned short* obuf = (unsigned short*)(big + (size_t)M * 3072 * 2);
  unsigned short* gbuf = (unsigned short*)big;

  f2bf_kernel<<<(3072 * 1024 / 4 + 255) / 256, 256, 0, stream>>>(qkvw, wqkv, 3072 * 1024 / 4);
  f2bf_kernel<<<(1024 * 1024 / 4 + 255) / 256, 256, 0, stream>>>(outw, wout, 1024 * 1024 / 4);
  f2bf_kernel<<<(4096 * 1024 / 4 + 255) / 256, 256, 0, stream>>>(fc1w, wfc1, 4096 * 1024 / 4);
  f2bf_kernel<<<(4096 * 1024 / 4 + 255) / 256, 256, 0, stream>>>(fc2w, wfc2, 4096 * 1024 / 4);

  // depth-0 reads x directly (no xb memcpy); out-proj writes xb at every depth
  for (int d = 0; d < 4; d++) {
    const float* cur = (d == 0) ? x : xb;
    rmsnorm_kernel<<<M, 256, 0, stream>>>(cur, n1w, xn);
    gemm_m256<0><<<dim3(3072 / 128, M / 256), 256, 0, stream>>>(xn, wqkv, qkvb, M, 3072, 1024);
    attn_kernel<<<dim3(T / 128, B * 16), 512, 0, stream>>>(qkvb, obuf);
    gemm_bf16<2><<<dim3(1024 / 128, M / 128), 256, 0, stream>>>(
        obuf, wout, xb, cur, nullptr, nullptr, 0, 0, M, 1024, 1024);
    rmsnorm_kernel<<<M, 256, 0, stream>>>(xb, n2w, xn);
    gemm_m256<1><<<dim3(4096 / 128, M / 256), 256, 0, stream>>>(xn, wfc1, gbuf, M, 4096, 1024);
    gemm_bf16<3><<<dim3(1024 / 128, M / 128), 256, 0, stream>>>(
        gbuf, wfc2, xb, xb, out, probs, d, d == 0 ? 1 : 0, M, 1024, 4096);
  }
}

// Round 19
// 1496.640 us; speedup vs baseline: 1.0641x; 1.0130x over previous
//
#include <hip/hip_runtime.h>
#include <cstdint>
#include <cstddef>

typedef __attribute__((ext_vector_type(8))) short bf16x8;
typedef __attribute__((ext_vector_type(4))) float f32x4;

#define DEV __device__ __forceinline__

DEV unsigned short f2bf(float f) {
  union { float f; unsigned u; } v; v.f = f;
  unsigned r = (v.u + 0x7FFFu + ((v.u >> 16) & 1u)) >> 16;   // RNE
  return (unsigned short)r;
}

DEV unsigned short f2bf_rtz(float f) {   // truncate: 1 op, fine for P (positive)
  union { float f; unsigned u; } v; v.f = f;
  return (unsigned short)(v.u >> 16);
}

DEV float bf2f(unsigned short h) {
  union { unsigned u; float f; } v; v.u = ((unsigned)h) << 16;
  return v.f;
}

// tanh-approx GELU in exp2 domain, NaN-safe form x - x/(1+u). |err| < ~1e-3.
DEV float gelu_fast(float x) {
  float x2 = x * x;
  float arg = x * fmaf(x2, 0.10294936f, 2.3021174f);
  float u = exp2f(arg);
  return x - x / (1.0f + u);
}

DEV void gload16(const void* g, void* l) {
  // async global->LDS, 16B per lane; LDS dest = wave-uniform base + lane*16
  __builtin_amdgcn_global_load_lds(
      (__attribute__((address_space(1))) void*)const_cast<void*>(g),
      (__attribute__((address_space(3))) void*)l,
      16, 0, 0);
}

// ---------------- elementwise kernels ----------------

__global__ __launch_bounds__(256) void f2bf_kernel(const float* __restrict__ in,
                                                   unsigned short* __restrict__ out, int n4) {
  int i = blockIdx.x * 256 + threadIdx.x;
  if (i < n4) {
    float4 v = ((const float4*)in)[i];
    ushort4 o;
    o.x = f2bf(v.x); o.y = f2bf(v.y); o.z = f2bf(v.z); o.w = f2bf(v.w);
    ((ushort4*)out)[i] = o;
  }
}

// rmsnorm over a 1024-elem row of bf16 input; bf16 output
__global__ __launch_bounds__(256) void rmsnorm_kernel(const unsigned short* __restrict__ x,
                                                      const float* __restrict__ w,
                                                      unsigned short* __restrict__ o) {
  const int row = blockIdx.x;
  const int tid = threadIdx.x;
  ushort4 u = ((const ushort4*)x)[(size_t)row * 256 + tid];
  float4 v;
  v.x = bf2f(u.x); v.y = bf2f(u.y); v.z = bf2f(u.z); v.w = bf2f(u.w);
  float s = v.x * v.x + v.y * v.y + v.z * v.z + v.w * v.w;
#pragma unroll
  for (int m = 32; m > 0; m >>= 1) s += __shfl_xor(s, m);
  __shared__ float red[4];
  if ((tid & 63) == 0) red[tid >> 6] = s;
  __syncthreads();
  float tot = red[0] + red[1] + red[2] + red[3];
  float inv = rsqrtf(tot * (1.0f / 1024.0f) + 1e-6f);
  float4 wv = ((const float4*)w)[tid];
  ushort4 ov;
  ov.x = f2bf(v.x * inv * wv.x);
  ov.y = f2bf(v.y * inv * wv.y);
  ov.z = f2bf(v.z * inv * wv.z);
  ov.w = f2bf(v.w * inv * wv.w);
  ((ushort4*)o)[(size_t)row * 256 + tid] = ov;
}

// ---------------- 128x128 GEMM (T2 swizzle + T1 raster) for N=1024: out, fc2 -
// Residual stream in bf16 (f32 math inside).
// EPI: 2 = xb16 = f2bf(bf2f(Res16) + acc)
//      3 = EPI2 + OutAcc(f32) (+)= probs[row,d] * (bf2f(Res16)+acc)
template <int EPI>
__global__ __launch_bounds__(256) void gemm_bf16(const unsigned short* __restrict__ A,
                                                 const unsigned short* __restrict__ W,
                                                 unsigned short* __restrict__ Of16,
                                                 const unsigned short* __restrict__ Res16,
                                                 float* __restrict__ OutAcc,
                                                 const float* __restrict__ probs,
                                                 int dIdx, int init,
                                                 int M, int N, int K) {
  __shared__ alignas(16) unsigned short As[128 * 64];
  __shared__ alignas(16) unsigned short Bs[128 * 64];
  const int tid = threadIdx.x;
  const int lane = tid & 63;
  const int wave = tid >> 6;
  const int wr = wave >> 1, wc = wave & 1;

  // XCD chunk + 8-row super-tile raster (nwg%8==0, gridDim.y%8==0)
  int bid = blockIdx.y * gridDim.x + blockIdx.x;
  const int nwg = gridDim.x * gridDim.y;
  bid = (bid & 7) * (nwg >> 3) + (bid >> 3);
  const int span = gridDim.x << 3;
  const int sg = bid / span;
  const int rem = bid % span;
  const int bx = rem >> 3;
  const int by = (sg << 3) + (rem & 7);

  const int brow = by * 128;
  const int bcol = bx * 128;

  f32x4 acc[4][4] = {};

  const int sr = tid >> 3;
  const int sc = ((tid & 7) ^ ((tid >> 3) & 7)) << 3;    // inverse-swizzled source col
  const int ro = lane & 15;
  const int rg = lane >> 4;
  const int rsw = (ro & 7) << 3;                         // read-side swizzle

  const unsigned short* aPtr = A + (size_t)(brow + sr) * K + sc;
  const unsigned short* wPtr = W + (size_t)(bcol + sr) * K + sc;
  const size_t rowStride32 = (size_t)32 * K;

  for (int kt = 0; kt < K; kt += 64) {
#pragma unroll
    for (int i = 0; i < 4; i++) {
      gload16(aPtr + i * rowStride32, &As[i * 2048 + wave * 512]);
      gload16(wPtr + i * rowStride32, &Bs[i * 2048 + wave * 512]);
    }
    aPtr += 64;
    wPtr += 64;
    __syncthreads();
#pragma unroll
    for (int kk = 0; kk < 2; kk++) {
      const int ko = kk * 32 + rg * 8;
      bf16x8 av[4], bv[4];
#pragma unroll
      for (int m2 = 0; m2 < 4; m2++)
        av[m2] = *(const bf16x8*)&As[(wr * 64 + m2 * 16 + ro) * 64 + (ko ^ rsw)];
#pragma unroll
      for (int n2 = 0; n2 < 4; n2++)
        bv[n2] = *(const bf16x8*)&Bs[(wc * 64 + n2 * 16 + ro) * 64 + (ko ^ rsw)];
#pragma unroll
      for (int m2 = 0; m2 < 4; m2++)
#pragma unroll
        for (int n2 = 0; n2 < 4; n2++)
          acc[m2][n2] = __builtin_amdgcn_mfma_f32_16x16x32_bf16(av[m2], bv[n2], acc[m2][n2], 0, 0, 0);
    }
    __syncthreads();
  }

#pragma unroll
  for (int m2 = 0; m2 < 4; m2++) {
#pragma unroll
    for (int i = 0; i < 4; i++) {
      const int row = brow + wr * 64 + m2 * 16 + rg * 4 + i;
#pragma unroll
      for (int n2 = 0; n2 < 4; n2++) {
        const int col = bcol + wc * 64 + n2 * 16 + ro;
        const size_t idx = (size_t)row * N + col;
        float v = acc[m2][n2][i];
        float nv = bf2f(Res16[idx]) + v;
        Of16[idx] = f2bf(nv);
        if (EPI == 3) {
          float p = probs[(size_t)row * 4 + dIdx];
          float o = init ? 0.f : OutAcc[idx];
          OutAcc[idx] = o + p * nv;
        }
      }
    }
  }
}

// ---------------- 256x128 GEMM, per-wave 128x64 (acc 8x4) for qkv & fc1 ------
// EPI: 0 = bf16 store with Q-prescale (cols<1024, for qkv), 1 = fast-gelu bf16.
template <int EPI>
__global__ __launch_bounds__(256, 2) void gemm_m256(const unsigned short* __restrict__ A,
                                                    const unsigned short* __restrict__ W,
                                                    unsigned short* __restrict__ Ob,
                                                    int M, int N, int K) {
  __shared__ alignas(16) unsigned short As[256 * 64];
  __shared__ alignas(16) unsigned short Bs[128 * 64];
  const int tid = threadIdx.x;
  const int lane = tid & 63;
  const int wave = tid >> 6;
  const int wr = wave >> 1, wc = wave & 1;

  // XCD chunk + 8-row super-tile raster (nwg%8==0, gridDim.y == M/256 == 32)
  int bid = blockIdx.y * gridDim.x + blockIdx.x;
  const int nwg = gridDim.x * gridDim.y;
  bid = (bid & 7) * (nwg >> 3) + (bid >> 3);
  const int span = gridDim.x << 3;
  const int sg = bid / span;
  const int rem = bid % span;
  const int bx = rem >> 3;
  const int by = (sg << 3) + (rem & 7);

  const int brow = by * 256;
  const int bcol = bx * 128;

  f32x4 acc[8][4] = {};

  const int sr = tid >> 3;
  const int sc = ((tid & 7) ^ ((tid >> 3) & 7)) << 3;    // inverse-swizzled source col
  const int ro = lane & 15;
  const int rg = lane >> 4;
  const int rsw = (ro & 7) << 3;                         // read-side swizzle

  const unsigned short* aPtr = A + (size_t)(brow + sr) * K + sc;
  const unsigned short* wPtr = W + (size_t)(bcol + sr) * K + sc;
  const size_t rowStride32 = (size_t)32 * K;

  for (int kt = 0; kt < K; kt += 64) {
#pragma unroll
    for (int i = 0; i < 8; i++)
      gload16(aPtr + i * rowStride32, &As[i * 2048 + wave * 512]);
#pragma unroll
    for (int i = 0; i < 4; i++)
      gload16(wPtr + i * rowStride32, &Bs[i * 2048 + wave * 512]);
    aPtr += 64;
    wPtr += 64;
    __syncthreads();
#pragma unroll
    for (int kk = 0; kk < 2; kk++) {
      const int ko = kk * 32 + rg * 8;
      bf16x8 av[8], bv[4];
#pragma unroll
      for (int m2 = 0; m2 < 8; m2++)
        av[m2] = *(const bf16x8*)&As[(wr * 128 + m2 * 16 + ro) * 64 + (ko ^ rsw)];
#pragma unroll
      for (int n2 = 0; n2 < 4; n2++)
        bv[n2] = *(const bf16x8*)&Bs[(wc * 64 + n2 * 16 + ro) * 64 + (ko ^ rsw)];
#pragma unroll
      for (int m2 = 0; m2 < 8; m2++)
#pragma unroll
        for (int n2 = 0; n2 < 4; n2++)
          acc[m2][n2] = __builtin_amdgcn_mfma_f32_16x16x32_bf16(av[m2], bv[n2], acc[m2][n2], 0, 0, 0);
    }
    __syncthreads();
  }

#pragma unroll
  for (int m2 = 0; m2 < 8; m2++) {
#pragma unroll
    for (int i = 0; i < 4; i++) {
      const int row = brow + wr * 128 + m2 * 16 + rg * 4 + i;
#pragma unroll
      for (int n2 = 0; n2 < 4; n2++) {
        const int col = bcol + wc * 64 + n2 * 16 + ro;
        const size_t idx = (size_t)row * N + col;
        float v = acc[m2][n2][i];
        if (EPI == 0) {
          float s2 = (col < 1024) ? 0.18033688f : 1.0f;   // pre-scale Q into log2 domain
          Ob[idx] = f2bf(v * s2);
        } else {
          Ob[idx] = f2bf(gelu_fast(v));
        }
      }
    }
  }
}

// ---------------- flash attention (r14, unchanged) ----------------
// 8 waves/block (512 thr), 128 q-rows/block, 16 q-rows/wave. One K/V stage
// serves 8 waves. (512,4): VGPR cap ~128, no spill; LDS 36.9KB -> 4 blk/CU.
__global__ __launch_bounds__(512, 4) void attn_kernel(const unsigned short* __restrict__ qkv,
                                                      unsigned short* __restrict__ ob) {
  __shared__ alignas(16) unsigned short kt[64][72];
  __shared__ alignas(16) unsigned short vt[64][72];
  __shared__ alignas(16) unsigned short pt[8][16][72];
  const int tid = threadIdx.x, lane = tid & 63, wave = tid >> 6;

  const int nwg = gridDim.x * gridDim.y;   // 1024, %8==0
  int bid = blockIdx.y * gridDim.x + blockIdx.x;
  bid = (bid & 7) * (nwg >> 3) + (bid >> 3);
  const int qt = bid % gridDim.x;
  const int bh = bid / gridDim.x;
  const int b = bh >> 4, h = bh & 15;

  const size_t base = (size_t)b * 1024 * 3072 + (size_t)h * 64;
  const unsigned short* qp = qkv + base;
  const int q0 = qt * 128 + wave * 16;
  const int ro = lane & 15, rg = lane >> 4;

  bf16x8 aq[2];
  aq[0] = *(const bf16x8*)&qp[(size_t)(q0 + ro) * 3072 + rg * 8];
  aq[1] = *(const bf16x8*)&qp[(size_t)(q0 + ro) * 3072 + 32 + rg * 8];

  // staging: 512 threads cover 64 rows x 64 cols in ONE pass (1 uint4 K + 1 uint4 V each)
  const int sr0 = tid >> 3, sci = tid & 7, scl = sci << 3;
  const unsigned short* kRow = qkv + base + 1024 + (size_t)sr0 * 3072 + scl;
  const unsigned short* vRow = qkv + base + 2048 + (size_t)sr0 * 3072 + scl;

  f32x4 oacc[4] = {};
  float mrow[4] = {-1e30f, -1e30f, -1e30f, -1e30f};  // group-uniform by construction
  float lrow[4] = {0.f, 0.f, 0.f, 0.f};              // per-lane partials, reduced at end

  for (int t0 = 0; t0 < 1024; t0 += 64) {
    {
      uint4 k0 = *(const uint4*)kRow;
      uint4 v0 = *(const uint4*)vRow;
      *(uint4*)&kt[sr0][scl] = k0;
      const unsigned short* e0 = (const unsigned short*)&v0;
#pragma unroll
      for (int j = 0; j < 8; j++) {
        const int jj = (j + sci) & 7;   // rotation: 8 same-row lanes -> 8 banks
        vt[scl + jj][sr0] = e0[jj];
      }
      kRow += 64 * 3072;
      vRow += 64 * 3072;
    }
    __syncthreads();

    // S = Q K^T  (Q pre-scaled by 1/8*log2e in the qkv GEMM epilogue)
    f32x4 sf[4] = {};
#pragma unroll
    for (int kk = 0; kk < 2; kk++) {
      const int ko = kk * 32 + rg * 8;
#pragma unroll
      for (int n2 = 0; n2 < 4; n2++) {
        bf16x8 bk = *(const bf16x8*)&kt[n2 * 16 + ro][ko];
        sf[n2] = __builtin_amdgcn_mfma_f32_16x16x32_bf16(aq[kk], bk, sf[n2], 0, 0, 0);
      }
    }

    // lane-local max only (no shuffles on common path)
    float lmax[4];
#pragma unroll
    for (int i = 0; i < 4; i++)
      lmax[i] = fmaxf(fmaxf(sf[0][i], sf[1][i]), fmaxf(sf[2][i], sf[3][i]));
    bool need = (lmax[0] > mrow[0] + 8.f) | (lmax[1] > mrow[1] + 8.f) |
                (lmax[2] > mrow[2] + 8.f) | (lmax[3] > mrow[3] + 8.f);
    if (__any(need)) {
#pragma unroll
      for (int msk = 1; msk < 16; msk <<= 1)
#pragma unroll
        for (int i = 0; i < 4; i++) lmax[i] = fmaxf(lmax[i], __shfl_xor(lmax[i], msk));
#pragma unroll
      for (int i = 0; i < 4; i++) {
        float mn = fmaxf(mrow[i], lmax[i]);
        float alpha = exp2f(mrow[i] - mn);   // group-uniform
        mrow[i] = mn;
        lrow[i] *= alpha;
#pragma unroll
        for (int n2 = 0; n2 < 4; n2++) oacc[n2][i] *= alpha;
      }
    }
#pragma unroll
    for (int n2 = 0; n2 < 4; n2++)
#pragma unroll
      for (int i = 0; i < 4; i++) {
        sf[n2][i] = exp2f(sf[n2][i] - mrow[i]);
        lrow[i] += sf[n2][i];
      }

#pragma unroll
    for (int n2 = 0; n2 < 4; n2++)
#pragma unroll
      for (int i = 0; i < 4; i++)
        pt[wave][rg * 4 + i][n2 * 16 + ro] = f2bf_rtz(sf[n2][i]);
    asm volatile("" ::: "memory");  // same-wave DS in-order; keep writes before reads

    // O += P @ V
#pragma unroll
    for (int kk = 0; kk < 2; kk++) {
      const int ko = kk * 32 + rg * 8;
      bf16x8 ap = *(const bf16x8*)&pt[wave][ro][ko];
#pragma unroll
      for (int n2 = 0; n2 < 4; n2++) {
        bf16x8 bv2 = *(const bf16x8*)&vt[n2 * 16 + ro][ko];
        oacc[n2] = __builtin_amdgcn_mfma_f32_16x16x32_bf16(ap, bv2, oacc[n2], 0, 0, 0);
      }
    }
    __syncthreads();
  }

  // final row-sum reduce across the 16-lane group
#pragma unroll
  for (int msk = 1; msk < 16; msk <<= 1)
#pragma unroll
    for (int i = 0; i < 4; i++) lrow[i] += __shfl_xor(lrow[i], msk);

#pragma unroll
  for (int n2 = 0; n2 < 4; n2++)
#pragma unroll
    for (int i = 0; i < 4; i++) {
      const int qrow = q0 + rg * 4 + i;
      float v = oacc[n2][i] / lrow[i];
      ob[((size_t)b * 1024 + qrow) * 1024 + h * 64 + n2 * 16 + ro] = f2bf(v);
    }
}

// ---------------- host ----------------

extern "C" void kernel_launch(void* const* d_in, const int* in_sizes, int n_in,
                              void* d_out, int out_size, void* d_ws, size_t ws_size,
                              hipStream_t stream) {
  const float* x = (const float*)d_in[0];
  const float* probs = (const float*)d_in[2];
  const float* n1w = (const float*)d_in[3];
  const float* qkvw = (const float*)d_in[4];
  const float* outw = (const float*)d_in[5];
  const float* n2w = (const float*)d_in[6];
  const float* fc1w = (const float*)d_in[7];
  const float* fc2w = (const float*)d_in[8];
  float* out = (float*)d_out;

  const int B = 8, T = 1024, C = 1024;
  const int M = B * T;  // 8192

  char* ws = (char*)d_ws;
  size_t off = 0;
  auto alloc = [&](size_t bytes) {
    void* p = ws + off;
    off += (bytes + 255) & ~(size_t)255;
    return p;
  };
  unsigned short* wqkv = (unsigned short*)alloc((size_t)3072 * 1024 * 2);
  unsigned short* wout = (unsigned short*)alloc((size_t)1024 * 1024 * 2);
  unsigned short* wfc1 = (unsigned short*)alloc((size_t)4096 * 1024 * 2);
  unsigned short* wfc2 = (unsigned short*)alloc((size_t)1024 * 4096 * 2);
  unsigned short* xb = (unsigned short*)alloc((size_t)M * C * 2);   // bf16 residual stream
  unsigned short* xn = (unsigned short*)alloc((size_t)M * C * 2);
  char* big = (char*)alloc((size_t)M * 4096 * 2);
  unsigned short* qkvb = (unsigned short*)big;
  unsigned short* obuf = (unsigned short*)(big + (size_t)M * 3072 * 2);
  unsigned short* gbuf = (unsigned short*)big;

  f2bf_kernel<<<(3072 * 1024 / 4 + 255) / 256, 256, 0, stream>>>(qkvw, wqkv, 3072 * 1024 / 4);
  f2bf_kernel<<<(1024 * 1024 / 4 + 255) / 256, 256, 0, stream>>>(outw, wout, 1024 * 1024 / 4);
  f2bf_kernel<<<(4096 * 1024 / 4 + 255) / 256, 256, 0, stream>>>(fc1w, wfc1, 4096 * 1024 / 4);
  f2bf_kernel<<<(4096 * 1024 / 4 + 255) / 256, 256, 0, stream>>>(fc2w, wfc2, 4096 * 1024 / 4);
  // residual stream -> bf16 working copy
  f2bf_kernel<<<(M * C / 4 + 255) / 256, 256, 0, stream>>>(x, xb, M * C / 4);

  for (int d = 0; d < 4; d++) {
    rmsnorm_kernel<<<M, 256, 0, stream>>>(xb, n1w, xn);
    gemm_m256<0><<<dim3(3072 / 128, M / 256), 256, 0, stream>>>(xn, wqkv, qkvb, M, 3072, 1024);
    attn_kernel<<<dim3(T / 128, B * 16), 512, 0, stream>>>(qkvb, obuf);
    gemm_bf16<2><<<dim3(1024 / 128, M / 128), 256, 0, stream>>>(
        obuf, wout, xb, xb, nullptr, nullptr, 0, 0, M, 1024, 1024);
    rmsnorm_kernel<<<M, 256, 0, stream>>>(xb, n2w, xn);
    gemm_m256<1><<<dim3(4096 / 128, M / 256), 256, 0, stream>>>(xn, wfc1, gbuf, M, 4096, 1024);
    gemm_bf16<3><<<dim3(1024 / 128, M / 128), 256, 0, stream>>>(
        gbuf, wfc2, xb, xb, out, probs, d, d == 0 ? 1 : 0, M, 1024, 4096);
  }
}